// Round 2
// baseline (814.438 us; speedup 1.0000x reference)
//
#include <hip/hip_runtime.h>
#include <hip/hip_bf16.h>

#define N_NODES 50000
#define N_EDGES 800000
#define FEAT    128
#define HID     128
#define NCLS    40

// ---------------- workspace layout ----------------
static constexpr size_t ALIGNB = 256;
static constexpr size_t aln(size_t x){ return (x + ALIGNB - 1) & ~(ALIGNB - 1); }
static constexpr size_t SZ_N_F     = aln((size_t)N_NODES * 4);
static constexpr size_t OFF_DEG_OUT = 0;
static constexpr size_t OFF_DEG_IN  = OFF_DEG_OUT + SZ_N_F;
static constexpr size_t OFF_ONORM   = OFF_DEG_IN  + SZ_N_F;
static constexpr size_t OFF_INORM   = OFF_ONORM   + SZ_N_F;
static constexpr size_t OFF_ROWPTR  = OFF_INORM   + SZ_N_F;
static constexpr size_t OFF_CURSOR  = OFF_ROWPTR  + aln((size_t)(N_NODES + 1) * 4);
static constexpr size_t OFF_ESRC    = OFF_CURSOR  + SZ_N_F;
static constexpr size_t OFF_HTMP    = OFF_ESRC    + aln((size_t)N_EDGES * 4);
static constexpr size_t OFF_XBUF    = OFF_HTMP    + aln((size_t)N_NODES * HID * 4);
// total ~55.6 MB

// ---------------- degree histogram ----------------
__global__ void k_degrees(const int* __restrict__ src, const int* __restrict__ dst,
                          float* __restrict__ dout, float* __restrict__ din){
  int e = blockIdx.x * 256 + threadIdx.x;
  if (e < N_EDGES){
    atomicAdd(&dout[src[e]], 1.0f);
    atomicAdd(&din[dst[e]], 1.0f);
  }
}

// ---------------- norms ----------------
__global__ void k_norms(const float* __restrict__ dout, const float* __restrict__ din,
                        float* __restrict__ onorm, float* __restrict__ inorm){
  int i = blockIdx.x * 256 + threadIdx.x;
  if (i < N_NODES){
    onorm[i] = rsqrtf(fmaxf(dout[i], 1.0f));
    inorm[i] = rsqrtf(fmaxf(din[i], 1.0f));
  }
}

// ---------------- single-block exclusive scan over in-degrees -> row_ptr ----------------
__global__ __launch_bounds__(1024) void k_scan(const float* __restrict__ din,
                                               int* __restrict__ rowptr){
  __shared__ int wsum[16];
  __shared__ int carry_s;
  const int t = threadIdx.x;
  const int lane = t & 63;
  const int w = t >> 6;
  if (t == 0) carry_s = 0;
  __syncthreads();
  for (int base = 0; base < N_NODES; base += 1024){
    int i = base + t;
    int v = (i < N_NODES) ? (int)din[i] : 0;
    int x = v;
    #pragma unroll
    for (int off = 1; off < 64; off <<= 1){
      int y = __shfl_up(x, off, 64);
      if (lane >= off) x += y;
    }
    if (lane == 63) wsum[w] = x;
    __syncthreads();
    if (w == 0 && lane < 16){
      int s = wsum[lane];
      #pragma unroll
      for (int off = 1; off < 16; off <<= 1){
        int y = __shfl_up(s, off, 64);
        if (lane >= off) s += y;
      }
      wsum[lane] = s;
    }
    __syncthreads();
    int c = carry_s;
    int woff = (w > 0) ? wsum[w - 1] : 0;
    if (i < N_NODES) rowptr[i] = c + woff + x - v;
    __syncthreads();
    if (t == 0) carry_s = c + wsum[15];
    __syncthreads();
  }
  if (t == 0) rowptr[N_NODES] = carry_s;
}

// ---------------- cursor init ----------------
__global__ void k_initcur(const int* __restrict__ rowptr, int* __restrict__ cursor){
  int i = blockIdx.x * 256 + threadIdx.x;
  if (i < N_NODES) cursor[i] = rowptr[i];
}

// ---------------- bucket edges by dst ----------------
__global__ void k_scatter(const int* __restrict__ src, const int* __restrict__ dst,
                          int* __restrict__ cursor, int* __restrict__ esrc){
  int e = blockIdx.x * 256 + threadIdx.x;
  if (e < N_EDGES){
    int d = dst[e];
    int pos = atomicAdd(&cursor[d], 1);
    esrc[pos] = src[e];
  }
}

// ---------------- GEMM: out[i][c] = onorm[i] * sum_k x[i][k] * W[k][c] ----------------
// block = 256 threads; CPAD columns per row-group (>=COLS, divides 256); RPT rows/thread.
template<int COLS, int CPAD, int RPT>
__global__ __launch_bounds__(256) void k_gemm(const float* __restrict__ xin,
                                              const float* __restrict__ Wg,
                                              const float* __restrict__ onorm,
                                              float* __restrict__ out){
  constexpr int GROUPS = 256 / CPAD;
  constexpr int ROWS = GROUPS * RPT;
  __shared__ __align__(16) float Wl[128 * COLS];
  __shared__ __align__(16) float Xl[ROWS][128];
  const int t = threadIdx.x;

  // stage W (fp32), float4
  const float4* W4 = (const float4*)Wg;
  for (int idx = t; idx < (128 * COLS) / 4; idx += 256){
    float4 p = W4[idx];
    float* d = &Wl[idx * 4];
    d[0]=p.x; d[1]=p.y; d[2]=p.z; d[3]=p.w;
  }

  const int row0 = blockIdx.x * ROWS;
  const float4* X4 = (const float4*)xin;            // row = 32 float4
  for (int idx = t; idx < ROWS * 32; idx += 256){
    int r = idx / 32, q = idx % 32;
    int gr = row0 + r;
    float4 p = make_float4(0.f, 0.f, 0.f, 0.f);
    if (gr < N_NODES) p = X4[(size_t)gr * 32 + q];
    float* d = &Xl[r][q * 4];
    d[0]=p.x; d[1]=p.y; d[2]=p.z; d[3]=p.w;
  }
  __syncthreads();

  const int g = t / CPAD;
  const int c = t % CPAD;
  if (c < COLS){
    float acc[RPT];
    #pragma unroll
    for (int j = 0; j < RPT; ++j) acc[j] = 0.f;
    #pragma unroll
    for (int k4 = 0; k4 < 32; ++k4){
      float4 xv[RPT];
      #pragma unroll
      for (int j = 0; j < RPT; ++j)
        xv[j] = ((const float4*)&Xl[g * RPT + j][0])[k4];
      #pragma unroll
      for (int kk = 0; kk < 4; ++kk){
        float wv = Wl[(k4 * 4 + kk) * COLS + c];
        #pragma unroll
        for (int j = 0; j < RPT; ++j){
          float xs = (kk == 0) ? xv[j].x : (kk == 1) ? xv[j].y : (kk == 2) ? xv[j].z : xv[j].w;
          acc[j] += xs * wv;
        }
      }
    }
    #pragma unroll
    for (int j = 0; j < RPT; ++j){
      int gr = row0 + g * RPT + j;
      if (gr < N_NODES)
        out[(size_t)gr * COLS + c] = onorm[gr] * acc[j];
    }
  }
}

// ---------------- CSR gather-aggregate + epilogue ----------------
template<int CW, int BDIM, bool RELU>
__global__ __launch_bounds__(BDIM) void k_aggregate(const float* __restrict__ htmp,
                                                    const int* __restrict__ rowptr,
                                                    const int* __restrict__ esrc,
                                                    const float* __restrict__ inorm,
                                                    const float* __restrict__ bias,
                                                    float* __restrict__ outf){
  __shared__ int es[128];
  const int node = blockIdx.x;
  const int t = threadIdx.x;
  const int start = rowptr[node], end = rowptr[node + 1];
  float acc = 0.f;
  for (int e0 = start; e0 < end; e0 += 128){
    int chunk = min(128, end - e0);
    __syncthreads();
    for (int j = t; j < chunk; j += BDIM) es[j] = esrc[e0 + j];
    __syncthreads();
    if (t < CW){
      for (int j = 0; j < chunk; ++j)
        acc += htmp[(size_t)es[j] * CW + t];
    }
  }
  if (t < CW){
    float y = acc * inorm[node] + bias[t];
    if (RELU) y = fmaxf(y, 0.f);
    outf[(size_t)node * CW + t] = y;
  }
}

// ---------------- launch ----------------
extern "C" void kernel_launch(void* const* d_in, const int* in_sizes, int n_in,
                              void* d_out, int out_size, void* d_ws, size_t ws_size,
                              hipStream_t stream){
  const float* feat = (const float*)d_in[0];
  const float* W1   = (const float*)d_in[1];
  const float* b1   = (const float*)d_in[2];
  const float* W2   = (const float*)d_in[3];
  const float* b2   = (const float*)d_in[4];
  const float* W3   = (const float*)d_in[5];
  const float* b3   = (const float*)d_in[6];
  const int* src = (const int*)d_in[7];
  const int* dst = (const int*)d_in[8];
  float* out = (float*)d_out;

  char* ws = (char*)d_ws;
  float* deg_out = (float*)(ws + OFF_DEG_OUT);
  float* deg_in  = (float*)(ws + OFF_DEG_IN);
  float* onorm   = (float*)(ws + OFF_ONORM);
  float* inorm   = (float*)(ws + OFF_INORM);
  int*   rowptr  = (int*)  (ws + OFF_ROWPTR);
  int*   cursor  = (int*)  (ws + OFF_CURSOR);
  int*   esrc    = (int*)  (ws + OFF_ESRC);
  float* htmp    = (float*)(ws + OFF_HTMP);
  float* xbuf    = (float*)(ws + OFF_XBUF);

  // zero degree histograms (deg_out, deg_in contiguous)
  hipMemsetAsync(deg_out, 0, 2 * SZ_N_F, stream);

  const int EB = (N_EDGES + 255) / 256;
  const int NB = (N_NODES + 255) / 256;
  k_degrees<<<EB, 256, 0, stream>>>(src, dst, deg_out, deg_in);
  k_scan   <<<1, 1024, 0, stream>>>(deg_in, rowptr);
  k_norms  <<<NB, 256, 0, stream>>>(deg_out, deg_in, onorm, inorm);
  k_initcur<<<NB, 256, 0, stream>>>(rowptr, cursor);
  k_scatter<<<EB, 256, 0, stream>>>(src, dst, cursor, esrc);

  // layer 1: htmp = onorm * (feat @ W1); xbuf = relu(agg * inorm + b1)
  k_gemm<128, 128, 4><<<(N_NODES + 7) / 8,  256, 0, stream>>>(feat, W1, onorm, htmp);
  k_aggregate<128, 128, true ><<<N_NODES, 128, 0, stream>>>(htmp, rowptr, esrc, inorm, b1, xbuf);
  // layer 2
  k_gemm<128, 128, 4><<<(N_NODES + 7) / 8,  256, 0, stream>>>(xbuf, W2, onorm, htmp);
  k_aggregate<128, 128, true ><<<N_NODES, 128, 0, stream>>>(htmp, rowptr, esrc, inorm, b2, xbuf);
  // layer 3 (40 classes, no relu)
  k_gemm<40, 64, 4><<<(N_NODES + 15) / 16, 256, 0, stream>>>(xbuf, W3, onorm, htmp);
  k_aggregate<40, 64, false><<<N_NODES, 64, 0, stream>>>(htmp, rowptr, esrc, inorm, b3, out);
}

// Round 3
// 493.801 us; speedup vs baseline: 1.6493x; 1.6493x over previous
//
#include <hip/hip_runtime.h>
#include <hip/hip_bf16.h>

#define N_NODES 50000
#define N_EDGES 800000
#define FEAT    128
#define HID     128
#define NCLS    40

// ---------------- workspace layout ----------------
static constexpr size_t ALIGNB = 256;
static constexpr size_t aln(size_t x){ return (x + ALIGNB - 1) & ~(ALIGNB - 1); }
static constexpr size_t SZ_N_F     = aln((size_t)N_NODES * 4);
static constexpr size_t OFF_DEG_OUT = 0;
static constexpr size_t OFF_DEG_IN  = OFF_DEG_OUT + SZ_N_F;
static constexpr size_t OFF_ONORM   = OFF_DEG_IN  + SZ_N_F;
static constexpr size_t OFF_INORM   = OFF_ONORM   + SZ_N_F;
static constexpr size_t OFF_ROWPTR  = OFF_INORM   + SZ_N_F;
static constexpr size_t OFF_CURSOR  = OFF_ROWPTR  + aln((size_t)(N_NODES + 1) * 4);
static constexpr size_t OFF_ESRC    = OFF_CURSOR  + SZ_N_F;
static constexpr size_t OFF_HTMP    = OFF_ESRC    + aln((size_t)N_EDGES * 4);
static constexpr size_t OFF_XBUF    = OFF_HTMP    + aln((size_t)N_NODES * HID * 4);

// ---------------- degree histogram ----------------
__global__ void k_degrees(const int* __restrict__ src, const int* __restrict__ dst,
                          float* __restrict__ dout, float* __restrict__ din){
  int e = blockIdx.x * 256 + threadIdx.x;
  if (e < N_EDGES){
    atomicAdd(&dout[src[e]], 1.0f);
    atomicAdd(&din[dst[e]], 1.0f);
  }
}

// ---------------- norms ----------------
__global__ void k_norms(const float* __restrict__ dout, const float* __restrict__ din,
                        float* __restrict__ onorm, float* __restrict__ inorm){
  int i = blockIdx.x * 256 + threadIdx.x;
  if (i < N_NODES){
    onorm[i] = rsqrtf(fmaxf(dout[i], 1.0f));
    inorm[i] = rsqrtf(fmaxf(din[i], 1.0f));
  }
}

// ---------------- single-block exclusive scan over in-degrees -> row_ptr ----------------
__global__ __launch_bounds__(1024) void k_scan(const float* __restrict__ din,
                                               int* __restrict__ rowptr){
  __shared__ int wsum[16];
  __shared__ int carry_s;
  const int t = threadIdx.x;
  const int lane = t & 63;
  const int w = t >> 6;
  if (t == 0) carry_s = 0;
  __syncthreads();
  for (int base = 0; base < N_NODES; base += 1024){
    int i = base + t;
    int v = (i < N_NODES) ? (int)din[i] : 0;
    int x = v;
    #pragma unroll
    for (int off = 1; off < 64; off <<= 1){
      int y = __shfl_up(x, off, 64);
      if (lane >= off) x += y;
    }
    if (lane == 63) wsum[w] = x;
    __syncthreads();
    if (w == 0 && lane < 16){
      int s = wsum[lane];
      #pragma unroll
      for (int off = 1; off < 16; off <<= 1){
        int y = __shfl_up(s, off, 64);
        if (lane >= off) s += y;
      }
      wsum[lane] = s;
    }
    __syncthreads();
    int c = carry_s;
    int woff = (w > 0) ? wsum[w - 1] : 0;
    if (i < N_NODES) rowptr[i] = c + woff + x - v;
    __syncthreads();
    if (t == 0) carry_s = c + wsum[15];
    __syncthreads();
  }
  if (t == 0) rowptr[N_NODES] = carry_s;
}

// ---------------- cursor init ----------------
__global__ void k_initcur(const int* __restrict__ rowptr, int* __restrict__ cursor){
  int i = blockIdx.x * 256 + threadIdx.x;
  if (i < N_NODES) cursor[i] = rowptr[i];
}

// ---------------- bucket edges by dst ----------------
__global__ void k_scatter(const int* __restrict__ src, const int* __restrict__ dst,
                          int* __restrict__ cursor, int* __restrict__ esrc){
  int e = blockIdx.x * 256 + threadIdx.x;
  if (e < N_EDGES){
    int d = dst[e];
    int pos = atomicAdd(&cursor[d], 1);
    esrc[pos] = src[e];
  }
}

// ---------------- register-tiled GEMM ----------------
// out[i][c] = onorm[i] * sum_k x[i][k] * W[k][c]
// Block: 256 threads = 16 row-groups (rg) x 16 col-groups (cg).
// Tile: 64 rows x COLS cols. Thread: RM=4 rows x RN cols (RN = COLS/16).
// X staged once: Xl[64][129] (pad -> 2-way banks, free).
// W staged per 32-k panel: Wl[32][COLS].
// COLS is padded compute width (128 or 64); WC = real W cols; OUTC = out stride.
template<int COLS, int WC, int OUTC>
__global__ __launch_bounds__(256) void k_gemm(const float* __restrict__ xin,
                                              const float* __restrict__ Wg,
                                              const float* __restrict__ onorm,
                                              float* __restrict__ out){
  constexpr int RN = COLS / 16;          // 8 or 4
  __shared__ __align__(16) float Xl[64][129];
  __shared__ __align__(16) float Wl[32][COLS];
  const int t = threadIdx.x;
  const int rg = t & 15;
  const int cg = t >> 4;
  const int row0 = blockIdx.x * 64;

  // ---- stage X tile (64 rows x 128 k), row-major, pad 129 ----
  {
    const float4* X4 = (const float4*)xin;
    #pragma unroll
    for (int i = 0; i < 8; ++i){
      int idx = t + i * 256;             // 2048 float4s
      int r = idx >> 5, q = idx & 31;
      int gr = row0 + r;
      float4 p = make_float4(0.f,0.f,0.f,0.f);
      if (gr < N_NODES) p = X4[(size_t)gr * 32 + q];
      Xl[r][q*4+0] = p.x; Xl[r][q*4+1] = p.y;
      Xl[r][q*4+2] = p.z; Xl[r][q*4+3] = p.w;
    }
  }

  float acc[4][RN];
  #pragma unroll
  for (int i = 0; i < 4; ++i)
    #pragma unroll
    for (int j = 0; j < RN; ++j) acc[i][j] = 0.f;

  const int r0 = rg * 4;
  const int c0 = cg * 4;

  // ---- k panels of 32 ----
  for (int p = 0; p < 4; ++p){
    const int k0 = p * 32;
    __syncthreads();
    // stage W panel: Wl[32][COLS]
    if (WC == COLS){
      const float4* W4 = (const float4*)Wg;
      constexpr int NQ = 32 * COLS / 4;          // float4 count
      #pragma unroll
      for (int i = 0; i < NQ / 256; ++i){
        int idx = t + i * 256;
        int k = idx / (COLS/4), q = idx % (COLS/4);
        float4 p = W4[(size_t)(k0 + k) * (COLS/4) + q];
        *(float4*)&Wl[k][q*4] = p;
      }
    } else {
      // WC=40 real cols, COLS=64 padded: 10 real float4s per k-row
      const float4* W4 = (const float4*)Wg;
      constexpr int NQ = 32 * COLS / 4;          // 512
      #pragma unroll
      for (int i = 0; i < NQ / 256; ++i){
        int idx = t + i * 256;
        int k = idx / (COLS/4), q = idx % (COLS/4);
        float4 p = make_float4(0.f,0.f,0.f,0.f);
        if (q < WC/4) p = W4[(size_t)(k0 + k) * (WC/4) + q];
        *(float4*)&Wl[k][q*4] = p;
      }
    }
    __syncthreads();

    #pragma unroll 8
    for (int k = 0; k < 32; ++k){
      const int kk = k0 + k;
      float xv[4];
      #pragma unroll
      for (int i = 0; i < 4; ++i) xv[i] = Xl[r0 + i][kk];
      float4 wA = *(const float4*)&Wl[k][c0];
      #pragma unroll
      for (int i = 0; i < 4; ++i){
        acc[i][0] += xv[i] * wA.x;
        acc[i][1] += xv[i] * wA.y;
        acc[i][2] += xv[i] * wA.z;
        acc[i][3] += xv[i] * wA.w;
      }
      if (RN == 8){
        float4 wB = *(const float4*)&Wl[k][c0 + 64];
        #pragma unroll
        for (int i = 0; i < 4; ++i){
          acc[i][4] += xv[i] * wB.x;
          acc[i][5] += xv[i] * wB.y;
          acc[i][6] += xv[i] * wB.z;
          acc[i][7] += xv[i] * wB.w;
        }
      }
    }
  }

  // ---- epilogue ----
  #pragma unroll
  for (int i = 0; i < 4; ++i){
    int gr = row0 + r0 + i;
    if (gr >= N_NODES) continue;
    float s = onorm[gr];
    if (c0 < WC){
      float4 v = make_float4(acc[i][0]*s, acc[i][1]*s, acc[i][2]*s, acc[i][3]*s);
      *(float4*)&out[(size_t)gr * OUTC + c0] = v;
    }
    if (RN == 8){
      float4 v = make_float4(acc[i][4]*s, acc[i][5]*s, acc[i][6]*s, acc[i][7]*s);
      *(float4*)&out[(size_t)gr * OUTC + c0 + 64] = v;
    }
  }
}

// ---------------- CSR gather-aggregate + epilogue ----------------
template<int CW, int BDIM, bool RELU>
__global__ __launch_bounds__(BDIM) void k_aggregate(const float* __restrict__ htmp,
                                                    const int* __restrict__ rowptr,
                                                    const int* __restrict__ esrc,
                                                    const float* __restrict__ inorm,
                                                    const float* __restrict__ bias,
                                                    float* __restrict__ outf){
  __shared__ int es[128];
  const int node = blockIdx.x;
  const int t = threadIdx.x;
  const int start = rowptr[node], end = rowptr[node + 1];
  float acc = 0.f;
  for (int e0 = start; e0 < end; e0 += 128){
    int chunk = min(128, end - e0);
    __syncthreads();
    for (int j = t; j < chunk; j += BDIM) es[j] = esrc[e0 + j];
    __syncthreads();
    if (t < CW){
      for (int j = 0; j < chunk; ++j)
        acc += htmp[(size_t)es[j] * CW + t];
    }
  }
  if (t < CW){
    float y = acc * inorm[node] + bias[t];
    if (RELU) y = fmaxf(y, 0.f);
    outf[(size_t)node * CW + t] = y;
  }
}

// ---------------- launch ----------------
extern "C" void kernel_launch(void* const* d_in, const int* in_sizes, int n_in,
                              void* d_out, int out_size, void* d_ws, size_t ws_size,
                              hipStream_t stream){
  const float* feat = (const float*)d_in[0];
  const float* W1   = (const float*)d_in[1];
  const float* b1   = (const float*)d_in[2];
  const float* W2   = (const float*)d_in[3];
  const float* b2   = (const float*)d_in[4];
  const float* W3   = (const float*)d_in[5];
  const float* b3   = (const float*)d_in[6];
  const int* src = (const int*)d_in[7];
  const int* dst = (const int*)d_in[8];
  float* out = (float*)d_out;

  char* ws = (char*)d_ws;
  float* deg_out = (float*)(ws + OFF_DEG_OUT);
  float* deg_in  = (float*)(ws + OFF_DEG_IN);
  float* onorm   = (float*)(ws + OFF_ONORM);
  float* inorm   = (float*)(ws + OFF_INORM);
  int*   rowptr  = (int*)  (ws + OFF_ROWPTR);
  int*   cursor  = (int*)  (ws + OFF_CURSOR);
  int*   esrc    = (int*)  (ws + OFF_ESRC);
  float* htmp    = (float*)(ws + OFF_HTMP);
  float* xbuf    = (float*)(ws + OFF_XBUF);

  hipMemsetAsync(deg_out, 0, 2 * SZ_N_F, stream);

  const int EB = (N_EDGES + 255) / 256;
  const int NB = (N_NODES + 255) / 256;
  k_degrees<<<EB, 256, 0, stream>>>(src, dst, deg_out, deg_in);
  k_scan   <<<1, 1024, 0, stream>>>(deg_in, rowptr);
  k_norms  <<<NB, 256, 0, stream>>>(deg_out, deg_in, onorm, inorm);
  k_initcur<<<NB, 256, 0, stream>>>(rowptr, cursor);
  k_scatter<<<EB, 256, 0, stream>>>(src, dst, cursor, esrc);

  const int GB = (N_NODES + 63) / 64;   // 782 blocks
  // layer 1
  k_gemm<128, 128, 128><<<GB, 256, 0, stream>>>(feat, W1, onorm, htmp);
  k_aggregate<128, 128, true ><<<N_NODES, 128, 0, stream>>>(htmp, rowptr, esrc, inorm, b1, xbuf);
  // layer 2
  k_gemm<128, 128, 128><<<GB, 256, 0, stream>>>(xbuf, W2, onorm, htmp);
  k_aggregate<128, 128, true ><<<N_NODES, 128, 0, stream>>>(htmp, rowptr, esrc, inorm, b2, xbuf);
  // layer 3 (40 cols padded to 64 compute)
  k_gemm<64, 40, 40><<<GB, 256, 0, stream>>>(xbuf, W3, onorm, htmp);
  k_aggregate<40, 64, false><<<N_NODES, 64, 0, stream>>>(htmp, rowptr, esrc, inorm, b3, out);
}